// Round 3
// baseline (85.158 us; speedup 1.0000x reference)
//
#include <hip/hip_runtime.h>
#include <hip/hip_bf16.h>

// Problem constants
#define NF 40   // fields f
#define NI 40   // in_sub i
#define NN 40   // out_sub n
#define ED 64   // embed D, d
#define NB 256  // batch b

typedef __attribute__((ext_vector_type(8))) short   short8;
typedef __attribute__((ext_vector_type(8))) __bf16  bf16x8;
typedef __attribute__((ext_vector_type(4))) float   f32x4;

__device__ __forceinline__ unsigned short f2bf(float x) {
    union { float f; unsigned u; } v; v.f = x;
    unsigned r = v.u + 0x7FFFu + ((v.u >> 16) & 1u);   // RNE
    return (unsigned short)(r >> 16);
}

__device__ __forceinline__ bf16x8 ld_frag(const unsigned short* p) {
    return __builtin_bit_cast(bf16x8, *(const short8*)p);
}

__device__ __forceinline__ f32x4 mfma16(bf16x8 a, bf16x8 b, f32x4 c) {
    return __builtin_amdgcn_mfma_f32_16x16x32_bf16(a, b, c, 0, 0, 0);
}

// ==========================================================================
// R14 architecture. Lessons:
//   R12: 256 MiB ws poison (~41 us) is UNCONDITIONAL -> ws is free, floor=41.
//   R13: main9 (grid 1280, 96 MFMA/wave) was LATENCY-bound: ~480 cy of MFMA
//        vs ~2000 cy of load latency/barriers per wave; b-tiles fetched x10.
// R14: pure b-major main. grid = 256 blocks x 512 thr (8 waves) = 1 block/CU.
//   - Each b's Bi/B0 loaded f32-coalesced + converted ONCE (no bft prep, no
//     tile redundancy). Swizzled LDS tile (verified R13 layout) -> conflict-
//     free ds_read_b128 fragments, loaded once per wave.
//   - Wave w handles n = k*8+w, k=0..4: per n, 14 param b128 loads from
//     L2-resident whp/alp ws + 48 MFMAs, all register-resident.
//   - 240 MFMA/wave, 2 waves/SIMD: latency finally has compute to hide under.
// prep4 (80 blocks, verified R5): whp[n][D][d]=W*h bf16; alp[n][i48][f64].
// ==========================================================================
#define WHP_N (64 * 64)   // 4096 shorts per n
#define ALP_N (48 * 64)   // 3072 shorts per n

// --------------------------------------------------------------------------
// prep4: 80 blocks x 256 thr (byte-identical to verified R5 version).
// --------------------------------------------------------------------------
__global__ __launch_bounds__(256) void gif_prep4(
        const float* __restrict__ W, const float* __restrict__ alpha,
        const float* __restrict__ h,
        unsigned short* __restrict__ whp, unsigned short* __restrict__ alp) {
    const int x = blockIdx.x;
    const int t = threadIdx.x;
    if (x < NN) {
        const int n = x;
        for (int idx = t; idx < 64 * 64; idx += 256) {       // whp coalesced
            int d = idx & 63;
            whp[n * WHP_N + idx] = f2bf(W[n * ED * ED + idx] * h[n * ED + d]);
        }
        for (int idx = t; idx < 8 * 64; idx += 256)          // rows i 40..47
            alp[n * ALP_N + (40 + (idx >> 6)) * 64 + (idx & 63)] = 0;
        for (int idx = t; idx < 40 * 24; idx += 256) {       // cols f 40..63
            int i = idx / 24, f = 40 + idx - i * 24;
            alp[n * ALP_N + i * 64 + f] = 0;
        }
    } else {
        const int f = x - NN;
        for (int idx = t; idx < NI * NN; idx += 256) {       // coalesced read
            int i = idx / NN, n = idx - i * NN;
            alp[n * ALP_N + i * 64 + f] = f2bf(alpha[(f * NI + i) * NN + n]);
        }
    }
}

// --------------------------------------------------------------------------
// main10: grid 256 x 512 thr (8 waves). Block = 1 b; wave w owns n = k*8+w.
// LDS tiles use the R13-verified XOR-chunk swizzle:
//   logical [row][f] at physical row*64 + (((f>>3) ^ (row&7))<<3) + (f&7)
// so stride-128B ds_read_b128 fragment reads are bank-conflict-free.
// --------------------------------------------------------------------------
__global__ __launch_bounds__(512, 2) void gif_main10(
        const float* __restrict__ B0, const float* __restrict__ Bi,
        const unsigned short* __restrict__ whp,
        const unsigned short* __restrict__ alp,
        float* __restrict__ out) {
    const int b = blockIdx.x;          // 0..255
    const int t = threadIdx.x;         // 0..511
    const int lane = t & 63, w = t >> 6;
    const int quad = lane >> 4, l15 = lane & 15, fo = quad * 8;

    __shared__ __align__(16) unsigned short sBi[48 * 64];   // [i][d] swizzled
    __shared__ __align__(16) unsigned short sBT[64 * 64];   // [D][f] swizzled

    // ---- 1. coalesced f32 tile loads (640 float4 each over 512 thr) ----
    float4 rb[2], r0[2];
    {
        const float4* biv = (const float4*)(Bi + (size_t)b * NI * ED);
        const float4* b0v = (const float4*)(B0 + (size_t)b * NF * ED);
#pragma unroll
        for (int k = 0; k < 2; ++k) {
            const int c = t + k * 512;
            if (c < 640) { rb[k] = biv[c]; r0[k] = b0v[c]; }
        }
    }

    // ---- 2. zero pads (swizzle-aware for sBT) ----
    for (int idx = t; idx < 8 * 64; idx += 512)          // sBi rows i 40..47
        sBi[(40 + (idx >> 6)) * 64 + (idx & 63)] = 0;
    for (int idx = t; idx < 64 * 24; idx += 512) {       // sBT logical f 40..63
        const int D = idx / 24, rem = idx - D * 24;
        const int c = 5 + (rem >> 3), j = rem & 7;       // logical chunks 5..7
        sBT[D * 64 + ((c ^ (D & 7)) << 3) + j] = 0;
    }

    // ---- 3. convert + write swizzled tiles ----
#pragma unroll
    for (int k = 0; k < 2; ++k) {
        const int c = t + k * 512;
        if (c < 640) {
            const int i = c >> 4, d0 = (c & 15) * 4;     // Bi row-major write
            ushort4 pk;
            pk.x = f2bf(rb[k].x); pk.y = f2bf(rb[k].y);
            pk.z = f2bf(rb[k].z); pk.w = f2bf(rb[k].w);
            const int chunk = (d0 >> 3) ^ (i & 7);
            *(ushort4*)&sBi[i * 64 + (chunk << 3) + (d0 & 7)] = pk;

            const int f = c >> 4, D0 = (c & 15) * 4;     // B0 transpose write
            const float fv[4] = {r0[k].x, r0[k].y, r0[k].z, r0[k].w};
#pragma unroll
            for (int r = 0; r < 4; ++r) {
                const int D = D0 + r;
                const int ch = (f >> 3) ^ (D & 7);
                sBT[D * 64 + (ch << 3) + (f & 7)] = f2bf(fv[r]);
            }
        }
    }
    __syncthreads();

    // ---- 4. per-wave b-tile fragments, loaded ONCE (conflict-free) ----
    bf16x8 biA[3][2], bb[4][2];
#pragma unroll
    for (int m = 0; m < 3; ++m)
#pragma unroll
        for (int s = 0; s < 2; ++s) {
            const int row = m * 16 + l15;
            const int pch = ((s * 4 + quad) ^ (row & 7)) << 3;
            biA[m][s] = ld_frag(&sBi[row * 64 + pch]);
        }
#pragma unroll
    for (int tt = 0; tt < 4; ++tt)
#pragma unroll
        for (int s = 0; s < 2; ++s) {
            const int row = tt * 16 + l15;
            const int pch = ((s * 4 + quad) ^ (row & 7)) << 3;
            bb[tt][s] = ld_frag(&sBT[row * 64 + pch]);
        }

    // ---- 5. n-loop: params from L2-resident ws + 48 MFMAs per n ----
#pragma unroll
    for (int k = 0; k < 5; ++k) {
        const int n = k * 8 + w;
        const unsigned short* ap = alp + (size_t)n * ALP_N;
        const unsigned short* wp = whp + (size_t)n * WHP_N;

        bf16x8 alA[3][2], whB[4][2];
#pragma unroll
        for (int m = 0; m < 3; ++m)
#pragma unroll
            for (int s = 0; s < 2; ++s)
                alA[m][s] = ld_frag(&ap[(m * 16 + l15) * 64 + s * 32 + fo]);
#pragma unroll
        for (int tt = 0; tt < 4; ++tt)
#pragma unroll
            for (int s = 0; s < 2; ++s)
                whB[tt][s] = ld_frag(&wp[(tt * 16 + l15) * 64 + s * 32 + fo]);

        float p[4];
#pragma unroll
        for (int tt = 0; tt < 4; ++tt) {
            float acc = 0.f;
#pragma unroll
            for (int m = 0; m < 3; ++m) {
                f32x4 z = {0.f, 0.f, 0.f, 0.f};
                f32x4 T = mfma16(biA[m][0], whB[tt][0], z);
                T = mfma16(biA[m][1], whB[tt][1], T);
                f32x4 G = mfma16(alA[m][0], bb[tt][0], z);
                G = mfma16(alA[m][1], bb[tt][1], G);
                acc += T[0] * G[0] + T[1] * G[1] + T[2] * G[2] + T[3] * G[3];
            }
            p[tt] = acc;
        }
#pragma unroll
        for (int tt = 0; tt < 4; ++tt) {
            p[tt] += __shfl_xor(p[tt], 16, 64);
            p[tt] += __shfl_xor(p[tt], 32, 64);
        }
        float v = (quad == 0) ? p[0] : (quad == 1) ? p[1] : (quad == 2) ? p[2] : p[3];
        out[((size_t)b * NN + n) * ED + lane] = v;
    }
}

// ==========================================================================
// TIER 0 (R2-verified): no-ws fallback.
// ==========================================================================
#define PS 72

__device__ __forceinline__ bf16x8 mk_al_frag(const float* __restrict__ alpha,
        int n, int m, int s, int l15, int quad) {
    bf16x8 r;
    const int row = m * 16 + l15;
    const int f0 = s * 32 + quad * 8;
#pragma unroll
    for (int j = 0; j < 8; ++j) {
        const int f = f0 + j;
        float v = (row < NI && f < NF) ? alpha[(f * NI + row) * NN + n] : 0.f;
        r[j] = (__bf16)v;
    }
    return r;
}
__device__ __forceinline__ bf16x8 mk_wh_frag(const float* __restrict__ W,
        const float* __restrict__ h, int n, int tt, int s, int l15, int quad) {
    bf16x8 r;
    const int row = tt * 16 + l15;
    const int k0 = s * 32 + quad * 8;
#pragma unroll
    for (int j = 0; j < 8; ++j) {
        float v = W[n * ED * ED + row * ED + k0 + j] * h[n * ED + k0 + j];
        r[j] = (__bf16)v;
    }
    return r;
}

__global__ __launch_bounds__(256) void gif_mfma(
        const float* __restrict__ B0, const float* __restrict__ Bi,
        const float* __restrict__ W, const float* __restrict__ alpha,
        const float* __restrict__ h, float* __restrict__ out) {
    const int q = blockIdx.x >> 8;
    const int b = blockIdx.x & 255;

    __shared__ __align__(16) unsigned short sBi[48 * PS];
    __shared__ __align__(16) unsigned short sBT[ED * PS];

    const int t = threadIdx.x;
    for (int idx = t; idx < 48 * PS; idx += 256) {
        int i = idx / PS, c = idx - i * PS;
        sBi[idx] = (i < NI && c < ED) ? f2bf(Bi[b * NI * ED + i * ED + c])
                                      : (unsigned short)0;
    }
    for (int idx = t; idx < ED * PS; idx += 256) {
        int D = idx / PS, c = idx - D * PS;
        sBT[idx] = (c < NF) ? f2bf(B0[b * NF * ED + c * ED + D])
                            : (unsigned short)0;
    }
    __syncthreads();

    const int lane = t & 63, w = t >> 6;
    const int quad = lane >> 4, l15 = lane & 15;
    const int fragoff = quad * 8;

    bf16x8 biA[3][2], b0B[4][2];
#pragma unroll
    for (int m = 0; m < 3; ++m)
#pragma unroll
        for (int s = 0; s < 2; ++s)
            biA[m][s] = ld_frag(&sBi[(m * 16 + l15) * PS + s * 32 + fragoff]);
#pragma unroll
    for (int tt = 0; tt < 4; ++tt)
#pragma unroll
        for (int s = 0; s < 2; ++s)
            b0B[tt][s] = ld_frag(&sBT[(tt * 16 + l15) * PS + s * 32 + fragoff]);

#pragma unroll
    for (int rep = 0; rep < 2; ++rep) {
        const int n = q * 8 + w + rep * 4;

        bf16x8 alA[3][2];
#pragma unroll
        for (int m = 0; m < 3; ++m)
#pragma unroll
            for (int s = 0; s < 2; ++s)
                alA[m][s] = mk_al_frag(alpha, n, m, s, l15, quad);

        float p[4];
#pragma unroll
        for (int tt = 0; tt < 4; ++tt) {
            bf16x8 whB2[2];
            whB2[0] = mk_wh_frag(W, h, n, tt, 0, l15, quad);
            whB2[1] = mk_wh_frag(W, h, n, tt, 1, l15, quad);
            float acc = 0.f;
#pragma unroll
            for (int m = 0; m < 3; ++m) {
                f32x4 z = {0.f, 0.f, 0.f, 0.f};
                f32x4 T = mfma16(biA[m][0], whB2[0], z);
                T = mfma16(biA[m][1], whB2[1], T);
                f32x4 G = mfma16(alA[m][0], b0B[tt][0], z);
                G = mfma16(alA[m][1], b0B[tt][1], G);
                acc += T[0] * G[0] + T[1] * G[1] + T[2] * G[2] + T[3] * G[3];
            }
            p[tt] = acc;
        }
#pragma unroll
        for (int tt = 0; tt < 4; ++tt) {
            p[tt] += __shfl_xor(p[tt], 16, 64);
            p[tt] += __shfl_xor(p[tt], 32, 64);
        }
        float v = (quad == 0) ? p[0] : (quad == 1) ? p[1] : (quad == 2) ? p[2] : p[3];
        out[(b * NN + n) * ED + lane] = v;
    }
}

// ==========================================================================
extern "C" void kernel_launch(void* const* d_in, const int* in_sizes, int n_in,
                              void* d_out, int out_size, void* d_ws, size_t ws_size,
                              hipStream_t stream) {
    const float* B0    = (const float*)d_in[0];  // (256,40,64)
    const float* Bi    = (const float*)d_in[1];  // (256,40,64)
    const float* W     = (const float*)d_in[2];  // (40,64,64)
    const float* alpha = (const float*)d_in[3];  // (40,40,40)
    const float* h     = (const float*)d_in[4];  // (40,64,1)
    float* out = (float*)d_out;                  // (256,40,64)

    const size_t need = (size_t)(NN * WHP_N + NN * ALP_N) * sizeof(unsigned short);
    if (ws_size >= need) {
        unsigned short* whp = (unsigned short*)d_ws;
        unsigned short* alp = whp + (size_t)NN * WHP_N;
        gif_prep4<<<NN + NF, 256, 0, stream>>>(W, alpha, h, whp, alp);
        gif_main10<<<NB, 512, 0, stream>>>(B0, Bi, whp, alp, out);
        return;
    }

    gif_mfma<<<5 * NB, 256, 0, stream>>>(B0, Bi, W, alpha, h, out);
}

// Round 4
// 80.974 us; speedup vs baseline: 1.0517x; 1.0517x over previous
//
#include <hip/hip_runtime.h>
#include <hip/hip_bf16.h>

// Problem constants
#define NF 40   // fields f
#define NI 40   // in_sub i
#define NN 40   // out_sub n
#define ED 64   // embed D, d
#define NB 256  // batch b

typedef __attribute__((ext_vector_type(8))) short   short8;
typedef __attribute__((ext_vector_type(8))) __bf16  bf16x8;
typedef __attribute__((ext_vector_type(4))) float   f32x4;

__device__ __forceinline__ unsigned short f2bf(float x) {
    union { float f; unsigned u; } v; v.f = x;
    unsigned r = v.u + 0x7FFFu + ((v.u >> 16) & 1u);   // RNE
    return (unsigned short)(r >> 16);
}

__device__ __forceinline__ bf16x8 ld_frag(const unsigned short* p) {
    return __builtin_bit_cast(bf16x8, *(const short8*)p);
}

__device__ __forceinline__ f32x4 mfma16(bf16x8 a, bf16x8 b, f32x4 c) {
    return __builtin_amdgcn_mfma_f32_16x16x32_bf16(a, b, c, 0, 0, 0);
}

// ==========================================================================
// R15 architecture. Traffic model fitted to R0-R3 (poison flushes L2 every
// iteration, so redundant reads are HBM):
//   traffic = params*(NB/bpb) + tiles*(NN/np);  R2: 109 MB, R3: 151 MB.
// R15 = R2's verified main9 with bpb 2->4 and 4 n's/block (grid 64x10):
//   params 36 MB + tiles 36 MB = 72 MB  (-37 MB vs R2).
// Schedule: stage(b0,b1) -> bar -> issue(b2,b3) loads early -> compute b0,b1
// (96 MFMA hides latency, T14) -> ds_write pair1 (disjoint region, no bar
// needed) -> bar -> compute b2,b3. Params in registers the whole kernel.
// XCD bonus: sharers of a b-tile (same bg, ng=0..9) are 64 apart in linear
// block id; 64%8==0 -> same XCD -> tile/param fetches dedup in that L2.
// prep5 byte-identical to verified R2.
// ==========================================================================
#define WHP_N (64 * 64)   // 4096 shorts per n
#define ALP_N (48 * 64)   // 3072 shorts per n
#define BFT_N 7168        // shorts per b: 48*64 (Bi) + 64*64 (B0T)
#define BI_OFF 0
#define B0T_OFF (48 * 64) // 3072
#define BPB 4             // b's per block in main

// --------------------------------------------------------------------------
// prep5: grid (NN + NF + NB) x 256.  [byte-identical to verified R2]
// --------------------------------------------------------------------------
__global__ __launch_bounds__(256) void gif_prep5(
        const float* __restrict__ B0, const float* __restrict__ Bi,
        const float* __restrict__ W, const float* __restrict__ alpha,
        const float* __restrict__ h,
        unsigned short* __restrict__ whp, unsigned short* __restrict__ alp,
        unsigned short* __restrict__ bft) {
    const int x = blockIdx.x;
    const int t = threadIdx.x;
    if (x < NN) {
        const int n = x;
        for (int idx = t; idx < 64 * 64; idx += 256) {       // whp coalesced
            int d = idx & 63;
            whp[n * WHP_N + idx] = f2bf(W[n * ED * ED + idx] * h[n * ED + d]);
        }
        for (int idx = t; idx < 8 * 64; idx += 256)          // alp rows i 40..47
            alp[n * ALP_N + (40 + (idx >> 6)) * 64 + (idx & 63)] = 0;
        for (int idx = t; idx < 40 * 24; idx += 256) {       // alp cols f 40..63
            int i = idx / 24, f = 40 + idx - i * 24;
            alp[n * ALP_N + i * 64 + f] = 0;
        }
    } else if (x < NN + NF) {
        const int f = x - NN;
        for (int idx = t; idx < NI * NN; idx += 256) {       // coalesced read
            int i = idx / NN, n = idx - i * NN;
            alp[n * ALP_N + i * 64 + f] = f2bf(alpha[(f * NI + i) * NN + n]);
        }
    } else {
        const int b = x - (NN + NF);
        unsigned short* dst = bft + (size_t)b * BFT_N;
        __shared__ __align__(16) unsigned short sT[64 * 72]; // B0T staging

        const float4* biv = (const float4*)(Bi + (size_t)b * NI * ED);
        const float4* b0v = (const float4*)(B0 + (size_t)b * NF * ED);
        float4 rb[3], r0[3];
#pragma unroll
        for (int k = 0; k < 3; ++k) {
            const int c = t + k * 256;
            if (c < 640) { rb[k] = biv[c]; r0[k] = b0v[c]; }
        }

        for (int idx = t; idx < 64 * 32; idx += 256)
            sT[(idx >> 5) * 72 + 40 + (idx & 31)] = 0;

#pragma unroll
        for (int k = 0; k < 3; ++k) {
            const int c = t + k * 256;
            if (c < 640) {
                const int i = c >> 4, d0 = (c & 15) * 4;
                ushort4 pk;
                pk.x = f2bf(rb[k].x); pk.y = f2bf(rb[k].y);
                pk.z = f2bf(rb[k].z); pk.w = f2bf(rb[k].w);
                const int chunk = (d0 >> 3) ^ (i & 7);
                *(ushort4*)&dst[BI_OFF + i * 64 + (chunk << 3) + (d0 & 7)] = pk;
            }
        }
        for (int idx = t; idx < 8 * 64; idx += 256)          // Bi pad rows
            dst[BI_OFF + (40 + (idx >> 6)) * 64 + (idx & 63)] = 0;

#pragma unroll
        for (int k = 0; k < 3; ++k) {
            const int c = t + k * 256;
            if (c < 640) {
                const int f = c >> 4, D0 = (c & 15) * 4;
                sT[(D0 + 0) * 72 + f] = f2bf(r0[k].x);
                sT[(D0 + 1) * 72 + f] = f2bf(r0[k].y);
                sT[(D0 + 2) * 72 + f] = f2bf(r0[k].z);
                sT[(D0 + 3) * 72 + f] = f2bf(r0[k].w);
            }
        }
        __syncthreads();

        for (int g = t; g < 512; g += 256) {
            const int D = g >> 3, pc = g & 7;
            short8 v = *(const short8*)&sT[D * 72 + ((pc ^ (D & 7)) << 3)];
            *(short8*)&dst[B0T_OFF + D * 64 + (pc << 3)] = v;
        }
    }
}

// --------------------------------------------------------------------------
// main11: grid (64, 10) x 256 thr (4 waves). Wave w owns n = ng*4 + w;
// block covers b in [bg*4, bg*4+4). Split-stage schedule (see header).
// --------------------------------------------------------------------------
__global__ __launch_bounds__(256) void gif_main11(
        const unsigned short* __restrict__ whp,
        const unsigned short* __restrict__ alp,
        const unsigned short* __restrict__ bft,
        float* __restrict__ out) {
    const int bg = blockIdx.x;         // 0..63 : b in [bg*4, bg*4+4)
    const int ng = blockIdx.y;         // 0..9  : n in [ng*4, ng*4+4)
    const int t = threadIdx.x;
    const int lane = t & 63, w = t >> 6;
    const int quad = lane >> 4, l15 = lane & 15, fo = quad * 8;
    const int n = ng * 4 + w;

    __shared__ __align__(16) unsigned short sBuf[4 * BFT_N];   // 57344 B

    // ---- 1. stage pair 0 (b0,b1): 7 coalesced b128 per thread ----
    short8 st[7];
    {
        const short8* src = (const short8*)(bft + (size_t)(bg * BPB) * BFT_N);
#pragma unroll
        for (int k = 0; k < 7; ++k) st[k] = src[t + k * 256];
    }

    // ---- 2. this wave's n-params: 14 b128 gathers (overlap with above) ----
    bf16x8 alA[3][2], whB[4][2];
    {
        const unsigned short* ap = alp + (size_t)n * ALP_N;
        const unsigned short* wp = whp + (size_t)n * WHP_N;
#pragma unroll
        for (int m = 0; m < 3; ++m)
#pragma unroll
            for (int s = 0; s < 2; ++s)
                alA[m][s] = ld_frag(&ap[(m * 16 + l15) * 64 + s * 32 + fo]);
#pragma unroll
        for (int tt = 0; tt < 4; ++tt)
#pragma unroll
            for (int s = 0; s < 2; ++s)
                whB[tt][s] = ld_frag(&wp[(tt * 16 + l15) * 64 + s * 32 + fo]);
    }

    // ---- 3. write pair 0 to LDS, barrier ----
#pragma unroll
    for (int k = 0; k < 7; ++k)
        *(short8*)&sBuf[(size_t)(t + k * 256) * 8] = st[k];
    __syncthreads();

    // ---- 4. issue pair 1 (b2,b3) global loads EARLY (hide under MFMA) ----
    {
        const short8* src = (const short8*)(bft + (size_t)(bg * BPB + 2) * BFT_N);
#pragma unroll
        for (int k = 0; k < 7; ++k) st[k] = src[t + k * 256];
    }

    // compute helper: one b from LDS buffer j (R2-verified body)
    auto compute = [&](int j) {
        const unsigned short* sb = &sBuf[j * BFT_N];
        const int b = bg * BPB + j;

        bf16x8 biA[3][2];
#pragma unroll
        for (int m = 0; m < 3; ++m)
#pragma unroll
            for (int s = 0; s < 2; ++s) {
                const int row = m * 16 + l15;
                const int pch = ((s * 4 + quad) ^ (row & 7)) << 3;
                biA[m][s] = ld_frag(&sb[BI_OFF + row * 64 + pch]);
            }

        float p[4];
#pragma unroll
        for (int tt = 0; tt < 4; ++tt) {
            const int row = tt * 16 + l15;
            const int pc0 = ((0 + quad) ^ (row & 7)) << 3;
            const int pc1 = ((4 + quad) ^ (row & 7)) << 3;
            bf16x8 bb0 = ld_frag(&sb[B0T_OFF + row * 64 + pc0]);
            bf16x8 bb1 = ld_frag(&sb[B0T_OFF + row * 64 + pc1]);
            float acc = 0.f;
#pragma unroll
            for (int m = 0; m < 3; ++m) {
                f32x4 z = {0.f, 0.f, 0.f, 0.f};
                f32x4 T = mfma16(biA[m][0], whB[tt][0], z);
                T = mfma16(biA[m][1], whB[tt][1], T);
                f32x4 G = mfma16(alA[m][0], bb0, z);
                G = mfma16(alA[m][1], bb1, G);
                acc += T[0] * G[0] + T[1] * G[1] + T[2] * G[2] + T[3] * G[3];
            }
            p[tt] = acc;
        }
#pragma unroll
        for (int tt = 0; tt < 4; ++tt) {
            p[tt] += __shfl_xor(p[tt], 16, 64);
            p[tt] += __shfl_xor(p[tt], 32, 64);
        }
        float v = (quad == 0) ? p[0] : (quad == 1) ? p[1] : (quad == 2) ? p[2] : p[3];
        out[((size_t)b * NN + n) * ED + lane] = v;
    };

    // ---- 5. compute pair 0 while pair-1 loads are in flight ----
    compute(0);
    compute(1);

    // ---- 6. write pair 1 (disjoint LDS region -> no barrier before) ----
#pragma unroll
    for (int k = 0; k < 7; ++k)
        *(short8*)&sBuf[2 * BFT_N + (size_t)(t + k * 256) * 8] = st[k];
    __syncthreads();

    // ---- 7. compute pair 1 ----
    compute(2);
    compute(3);
}

// ==========================================================================
// TIER 0 (R2-verified): no-ws fallback.
// ==========================================================================
#define PS 72

__device__ __forceinline__ bf16x8 mk_al_frag(const float* __restrict__ alpha,
        int n, int m, int s, int l15, int quad) {
    bf16x8 r;
    const int row = m * 16 + l15;
    const int f0 = s * 32 + quad * 8;
#pragma unroll
    for (int j = 0; j < 8; ++j) {
        const int f = f0 + j;
        float v = (row < NI && f < NF) ? alpha[(f * NI + row) * NN + n] : 0.f;
        r[j] = (__bf16)v;
    }
    return r;
}
__device__ __forceinline__ bf16x8 mk_wh_frag(const float* __restrict__ W,
        const float* __restrict__ h, int n, int tt, int s, int l15, int quad) {
    bf16x8 r;
    const int row = tt * 16 + l15;
    const int k0 = s * 32 + quad * 8;
#pragma unroll
    for (int j = 0; j < 8; ++j) {
        float v = W[n * ED * ED + row * ED + k0 + j] * h[n * ED + k0 + j];
        r[j] = (__bf16)v;
    }
    return r;
}

__global__ __launch_bounds__(256) void gif_mfma(
        const float* __restrict__ B0, const float* __restrict__ Bi,
        const float* __restrict__ W, const float* __restrict__ alpha,
        const float* __restrict__ h, float* __restrict__ out) {
    const int q = blockIdx.x >> 8;
    const int b = blockIdx.x & 255;

    __shared__ __align__(16) unsigned short sBi[48 * PS];
    __shared__ __align__(16) unsigned short sBT[ED * PS];

    const int t = threadIdx.x;
    for (int idx = t; idx < 48 * PS; idx += 256) {
        int i = idx / PS, c = idx - i * PS;
        sBi[idx] = (i < NI && c < ED) ? f2bf(Bi[b * NI * ED + i * ED + c])
                                      : (unsigned short)0;
    }
    for (int idx = t; idx < ED * PS; idx += 256) {
        int D = idx / PS, c = idx - D * PS;
        sBT[idx] = (c < NF) ? f2bf(B0[b * NF * ED + c * ED + D])
                            : (unsigned short)0;
    }
    __syncthreads();

    const int lane = t & 63, w = t >> 6;
    const int quad = lane >> 4, l15 = lane & 15;
    const int fragoff = quad * 8;

    bf16x8 biA[3][2], b0B[4][2];
#pragma unroll
    for (int m = 0; m < 3; ++m)
#pragma unroll
        for (int s = 0; s < 2; ++s)
            biA[m][s] = ld_frag(&sBi[(m * 16 + l15) * PS + s * 32 + fragoff]);
#pragma unroll
    for (int tt = 0; tt < 4; ++tt)
#pragma unroll
        for (int s = 0; s < 2; ++s)
            b0B[tt][s] = ld_frag(&sBT[(tt * 16 + l15) * PS + s * 32 + fragoff]);

#pragma unroll
    for (int rep = 0; rep < 2; ++rep) {
        const int n = q * 8 + w + rep * 4;

        bf16x8 alA[3][2];
#pragma unroll
        for (int m = 0; m < 3; ++m)
#pragma unroll
            for (int s = 0; s < 2; ++s)
                alA[m][s] = mk_al_frag(alpha, n, m, s, l15, quad);

        float p[4];
#pragma unroll
        for (int tt = 0; tt < 4; ++tt) {
            bf16x8 whB2[2];
            whB2[0] = mk_wh_frag(W, h, n, tt, 0, l15, quad);
            whB2[1] = mk_wh_frag(W, h, n, tt, 1, l15, quad);
            float acc = 0.f;
#pragma unroll
            for (int m = 0; m < 3; ++m) {
                f32x4 z = {0.f, 0.f, 0.f, 0.f};
                f32x4 T = mfma16(biA[m][0], whB2[0], z);
                T = mfma16(biA[m][1], whB2[1], T);
                f32x4 G = mfma16(alA[m][0], b0B[tt][0], z);
                G = mfma16(alA[m][1], b0B[tt][1], G);
                acc += T[0] * G[0] + T[1] * G[1] + T[2] * G[2] + T[3] * G[3];
            }
            p[tt] = acc;
        }
#pragma unroll
        for (int tt = 0; tt < 4; ++tt) {
            p[tt] += __shfl_xor(p[tt], 16, 64);
            p[tt] += __shfl_xor(p[tt], 32, 64);
        }
        float v = (quad == 0) ? p[0] : (quad == 1) ? p[1] : (quad == 2) ? p[2] : p[3];
        out[(b * NN + n) * ED + lane] = v;
    }
}

// ==========================================================================
extern "C" void kernel_launch(void* const* d_in, const int* in_sizes, int n_in,
                              void* d_out, int out_size, void* d_ws, size_t ws_size,
                              hipStream_t stream) {
    const float* B0    = (const float*)d_in[0];  // (256,40,64)
    const float* Bi    = (const float*)d_in[1];  // (256,40,64)
    const float* W     = (const float*)d_in[2];  // (40,64,64)
    const float* alpha = (const float*)d_in[3];  // (40,40,40)
    const float* h     = (const float*)d_in[4];  // (40,64,1)
    float* out = (float*)d_out;                  // (256,40,64)

    const size_t need = (size_t)(NN * WHP_N + NN * ALP_N + NB * BFT_N)
                        * sizeof(unsigned short);
    if (ws_size >= need) {
        unsigned short* whp = (unsigned short*)d_ws;
        unsigned short* alp = whp + (size_t)NN * WHP_N;
        unsigned short* bft = alp + (size_t)NN * ALP_N;
        gif_prep5<<<NN + NF + NB, 256, 0, stream>>>(B0, Bi, W, alpha, h,
                                                    whp, alp, bft);
        gif_main11<<<dim3(NB / BPB, 10), 256, 0, stream>>>(whp, alp, bft, out);
        return;
    }

    gif_mfma<<<5 * NB, 256, 0, stream>>>(B0, Bi, W, alpha, h, out);
}

// Round 5
// 80.169 us; speedup vs baseline: 1.0622x; 1.0100x over previous
//
#include <hip/hip_runtime.h>
#include <hip/hip_bf16.h>

// Problem constants
#define NF 40   // fields f
#define NI 40   // in_sub i
#define NN 40   // out_sub n
#define ED 64   // embed D, d
#define NB 256  // batch b

typedef __attribute__((ext_vector_type(8))) short   short8;
typedef __attribute__((ext_vector_type(8))) __bf16  bf16x8;
typedef __attribute__((ext_vector_type(4))) float   f32x4;

__device__ __forceinline__ unsigned short f2bf(float x) {
    union { float f; unsigned u; } v; v.f = x;
    unsigned r = v.u + 0x7FFFu + ((v.u >> 16) & 1u);   // RNE
    return (unsigned short)(r >> 16);
}

__device__ __forceinline__ bf16x8 ld_frag(const unsigned short* p) {
    return __builtin_bit_cast(bf16x8, *(const short8*)p);
}

__device__ __forceinline__ f32x4 mfma16(bf16x8 a, bf16x8 b, f32x4 c) {
    return __builtin_amdgcn_mfma_f32_16x16x32_bf16(a, b, c, 0, 0, 0);
}

// ==========================================================================
// R16 = revert to R2 (best measured: 79.6 us). Session conclusion:
//   dur = 41.5 us unconditional 256 MiB ws poison (81% HBM peak, untouchable)
//       + ~32 us harness reset()-dispatch overhead (dozens of tiny memsets,
//         fixed regardless of kernel structure: R0-R4 non-fill = 38-44 us
//         across 5 structurally different implementations)
//       + ~5 us our kernels (prep5 + main9, latency-bound, <7% of wall).
// Traffic-reduction (R4: 109->72 MB) and b-major (R3) both failed to beat
// this because redundant param reads were L2/L3 hits, not HBM.
//   ws layout:
//     whp[n][D64][d64]  bf16  (W*h, fragment-ready)
//     alp[n][i48][f64]  bf16  (alpha^T, pads zeroed)
//     bft[b] = { Bi[i48][d64] | B0T[D64][f64] } bf16, swizzled, pads zeroed
// main9: 7 coalesced b128 loads + 7 linear ds_write_b128 per thread (both
// b's), param gathers, ONE __syncthreads, then pure MFMA.
// ==========================================================================
#define WHP_N (64 * 64)   // 4096 shorts per n
#define ALP_N (48 * 64)   // 3072 shorts per n
#define BFT_N 7168        // shorts per b: 48*64 (Bi) + 64*64 (B0T)
#define BI_OFF 0
#define B0T_OFF (48 * 64) // 3072
#define BPB 2             // b's per block in main

// --------------------------------------------------------------------------
// prep5: grid (NN + NF + NB) x 256.
// --------------------------------------------------------------------------
__global__ __launch_bounds__(256) void gif_prep5(
        const float* __restrict__ B0, const float* __restrict__ Bi,
        const float* __restrict__ W, const float* __restrict__ alpha,
        const float* __restrict__ h,
        unsigned short* __restrict__ whp, unsigned short* __restrict__ alp,
        unsigned short* __restrict__ bft) {
    const int x = blockIdx.x;
    const int t = threadIdx.x;
    if (x < NN) {
        const int n = x;
        for (int idx = t; idx < 64 * 64; idx += 256) {       // whp coalesced
            int d = idx & 63;
            whp[n * WHP_N + idx] = f2bf(W[n * ED * ED + idx] * h[n * ED + d]);
        }
        for (int idx = t; idx < 8 * 64; idx += 256)          // alp rows i 40..47
            alp[n * ALP_N + (40 + (idx >> 6)) * 64 + (idx & 63)] = 0;
        for (int idx = t; idx < 40 * 24; idx += 256) {       // alp cols f 40..63
            int i = idx / 24, f = 40 + idx - i * 24;
            alp[n * ALP_N + i * 64 + f] = 0;
        }
    } else if (x < NN + NF) {
        const int f = x - NN;
        for (int idx = t; idx < NI * NN; idx += 256) {       // coalesced read
            int i = idx / NN, n = idx - i * NN;
            alp[n * ALP_N + i * 64 + f] = f2bf(alpha[(f * NI + i) * NN + n]);
        }
    } else {
        const int b = x - (NN + NF);
        unsigned short* dst = bft + (size_t)b * BFT_N;
        __shared__ __align__(16) unsigned short sT[64 * 72]; // B0T staging

        // coalesced float4 reads of this b's Bi and B0
        const float4* biv = (const float4*)(Bi + (size_t)b * NI * ED);
        const float4* b0v = (const float4*)(B0 + (size_t)b * NF * ED);
        float4 rb[3], r0[3];
#pragma unroll
        for (int k = 0; k < 3; ++k) {
            const int c = t + k * 256;
            if (c < 640) { rb[k] = biv[c]; r0[k] = b0v[c]; }
        }

        // zero sT pad cols f 40..71 (only 40..63 ever read)
        for (int idx = t; idx < 64 * 32; idx += 256)
            sT[(idx >> 5) * 72 + 40 + (idx & 31)] = 0;

        // Bi: write swizzled bf16 rows directly (ushort4, 8B aligned)
#pragma unroll
        for (int k = 0; k < 3; ++k) {
            const int c = t + k * 256;
            if (c < 640) {
                const int i = c >> 4, d0 = (c & 15) * 4;
                ushort4 pk;
                pk.x = f2bf(rb[k].x); pk.y = f2bf(rb[k].y);
                pk.z = f2bf(rb[k].z); pk.w = f2bf(rb[k].w);
                const int chunk = (d0 >> 3) ^ (i & 7);
                *(ushort4*)&dst[BI_OFF + i * 64 + (chunk << 3) + (d0 & 7)] = pk;
            }
        }
        for (int idx = t; idx < 8 * 64; idx += 256)          // Bi pad rows
            dst[BI_OFF + (40 + (idx >> 6)) * 64 + (idx & 63)] = 0;

        // B0 -> sT transpose (sT[D][f] = B0[b][f][D])
#pragma unroll
        for (int k = 0; k < 3; ++k) {
            const int c = t + k * 256;
            if (c < 640) {
                const int f = c >> 4, D0 = (c & 15) * 4;
                sT[(D0 + 0) * 72 + f] = f2bf(r0[k].x);
                sT[(D0 + 1) * 72 + f] = f2bf(r0[k].y);
                sT[(D0 + 2) * 72 + f] = f2bf(r0[k].z);
                sT[(D0 + 3) * 72 + f] = f2bf(r0[k].w);
            }
        }
        __syncthreads();

        // sT -> dst B0T, swizzled, coalesced short8 writes
        for (int g = t; g < 512; g += 256) {
            const int D = g >> 3, pc = g & 7;        // physical chunk pc
            short8 v = *(const short8*)&sT[D * 72 + ((pc ^ (D & 7)) << 3)];
            *(short8*)&dst[B0T_OFF + D * 64 + (pc << 3)] = v;
        }
    }
}

// --------------------------------------------------------------------------
// main9: grid (128, 10) x 256 thr (4 waves). Wave w owns n = ng*4 + w.
// --------------------------------------------------------------------------
__global__ __launch_bounds__(256, 2) void gif_main9(
        const unsigned short* __restrict__ whp,
        const unsigned short* __restrict__ alp,
        const unsigned short* __restrict__ bft,
        float* __restrict__ out) {
    const int bg = blockIdx.x;         // 0..127 : b in [bg*2, bg*2+2)
    const int ng = blockIdx.y;         // 0..9   : n in [ng*4, ng*4+4)
    const int t = threadIdx.x;
    const int lane = t & 63, w = t >> 6;
    const int quad = lane >> 4, l15 = lane & 15, fo = quad * 8;
    const int n = ng * 4 + w;

    __shared__ __align__(16) unsigned short sBuf[2 * BFT_N];   // 28672 B

    // ---- 1. register-stage BOTH b's tiles: 7 coalesced b128 per thread ----
    const short8* src = (const short8*)(bft + (size_t)(bg * BPB) * BFT_N);
    short8 st[7];
#pragma unroll
    for (int k = 0; k < 7; ++k) st[k] = src[t + k * 256];   // 1792 = 7*256

    // ---- 2. this wave's n-params: 14 b128 gathers (overlap with above) ----
    bf16x8 alA[3][2], whB[4][2];
    {
        const unsigned short* ap = alp + n * ALP_N;
        const unsigned short* wp = whp + n * WHP_N;
#pragma unroll
        for (int m = 0; m < 3; ++m)
#pragma unroll
            for (int s = 0; s < 2; ++s)
                alA[m][s] = ld_frag(&ap[(m * 16 + l15) * 64 + s * 32 + fo]);
#pragma unroll
        for (int tt = 0; tt < 4; ++tt)
#pragma unroll
            for (int s = 0; s < 2; ++s)
                whB[tt][s] = ld_frag(&wp[(tt * 16 + l15) * 64 + s * 32 + fo]);
    }

    // ---- 3. linear conflict-free ds_write_b128, ONE barrier ----
#pragma unroll
    for (int k = 0; k < 7; ++k)
        *(short8*)&sBuf[(size_t)(t + k * 256) * 8] = st[k];
    __syncthreads();

    // ---- 4. two b's, pure MFMA (no further barriers) ----
#pragma unroll
    for (int j = 0; j < BPB; ++j) {
        const unsigned short* sb = &sBuf[j * BFT_N];
        const int b = bg * BPB + j;

        bf16x8 biA[3][2];
#pragma unroll
        for (int m = 0; m < 3; ++m)
#pragma unroll
            for (int s = 0; s < 2; ++s) {
                const int row = m * 16 + l15;
                const int pch = ((s * 4 + quad) ^ (row & 7)) << 3;
                biA[m][s] = ld_frag(&sb[BI_OFF + row * 64 + pch]);
            }

        float p[4];
#pragma unroll
        for (int tt = 0; tt < 4; ++tt) {
            const int row = tt * 16 + l15;
            const int pc0 = ((0 + quad) ^ (row & 7)) << 3;
            const int pc1 = ((4 + quad) ^ (row & 7)) << 3;
            bf16x8 bb0 = ld_frag(&sb[B0T_OFF + row * 64 + pc0]);
            bf16x8 bb1 = ld_frag(&sb[B0T_OFF + row * 64 + pc1]);
            float acc = 0.f;
#pragma unroll
            for (int m = 0; m < 3; ++m) {
                f32x4 z = {0.f, 0.f, 0.f, 0.f};
                f32x4 T = mfma16(biA[m][0], whB[tt][0], z);
                T = mfma16(biA[m][1], whB[tt][1], T);
                f32x4 G = mfma16(alA[m][0], bb0, z);
                G = mfma16(alA[m][1], bb1, G);
                acc += T[0] * G[0] + T[1] * G[1] + T[2] * G[2] + T[3] * G[3];
            }
            p[tt] = acc;
        }
#pragma unroll
        for (int tt = 0; tt < 4; ++tt) {
            p[tt] += __shfl_xor(p[tt], 16, 64);
            p[tt] += __shfl_xor(p[tt], 32, 64);
        }
        float v = (quad == 0) ? p[0] : (quad == 1) ? p[1] : (quad == 2) ? p[2] : p[3];
        out[((size_t)b * NN + n) * ED + lane] = v;
    }
}

// ==========================================================================
// TIER 0 (R2-verified): no-ws fallback.
// ==========================================================================
#define PS 72

__device__ __forceinline__ bf16x8 mk_al_frag(const float* __restrict__ alpha,
        int n, int m, int s, int l15, int quad) {
    bf16x8 r;
    const int row = m * 16 + l15;
    const int f0 = s * 32 + quad * 8;
#pragma unroll
    for (int j = 0; j < 8; ++j) {
        const int f = f0 + j;
        float v = (row < NI && f < NF) ? alpha[(f * NI + row) * NN + n] : 0.f;
        r[j] = (__bf16)v;
    }
    return r;
}
__device__ __forceinline__ bf16x8 mk_wh_frag(const float* __restrict__ W,
        const float* __restrict__ h, int n, int tt, int s, int l15, int quad) {
    bf16x8 r;
    const int row = tt * 16 + l15;
    const int k0 = s * 32 + quad * 8;
#pragma unroll
    for (int j = 0; j < 8; ++j) {
        float v = W[n * ED * ED + row * ED + k0 + j] * h[n * ED + k0 + j];
        r[j] = (__bf16)v;
    }
    return r;
}

__global__ __launch_bounds__(256) void gif_mfma(
        const float* __restrict__ B0, const float* __restrict__ Bi,
        const float* __restrict__ W, const float* __restrict__ alpha,
        const float* __restrict__ h, float* __restrict__ out) {
    const int q = blockIdx.x >> 8;
    const int b = blockIdx.x & 255;

    __shared__ __align__(16) unsigned short sBi[48 * PS];
    __shared__ __align__(16) unsigned short sBT[ED * PS];

    const int t = threadIdx.x;
    for (int idx = t; idx < 48 * PS; idx += 256) {
        int i = idx / PS, c = idx - i * PS;
        sBi[idx] = (i < NI && c < ED) ? f2bf(Bi[b * NI * ED + i * ED + c])
                                      : (unsigned short)0;
    }
    for (int idx = t; idx < ED * PS; idx += 256) {
        int D = idx / PS, c = idx - D * PS;
        sBT[idx] = (c < NF) ? f2bf(B0[b * NF * ED + c * ED + D])
                            : (unsigned short)0;
    }
    __syncthreads();

    const int lane = t & 63, w = t >> 6;
    const int quad = lane >> 4, l15 = lane & 15;
    const int fragoff = quad * 8;

    bf16x8 biA[3][2], b0B[4][2];
#pragma unroll
    for (int m = 0; m < 3; ++m)
#pragma unroll
        for (int s = 0; s < 2; ++s)
            biA[m][s] = ld_frag(&sBi[(m * 16 + l15) * PS + s * 32 + fragoff]);
#pragma unroll
    for (int tt = 0; tt < 4; ++tt)
#pragma unroll
        for (int s = 0; s < 2; ++s)
            b0B[tt][s] = ld_frag(&sBT[(tt * 16 + l15) * PS + s * 32 + fragoff]);

#pragma unroll
    for (int rep = 0; rep < 2; ++rep) {
        const int n = q * 8 + w + rep * 4;

        bf16x8 alA[3][2];
#pragma unroll
        for (int m = 0; m < 3; ++m)
#pragma unroll
            for (int s = 0; s < 2; ++s)
                alA[m][s] = mk_al_frag(alpha, n, m, s, l15, quad);

        float p[4];
#pragma unroll
        for (int tt = 0; tt < 4; ++tt) {
            bf16x8 whB2[2];
            whB2[0] = mk_wh_frag(W, h, n, tt, 0, l15, quad);
            whB2[1] = mk_wh_frag(W, h, n, tt, 1, l15, quad);
            float acc = 0.f;
#pragma unroll
            for (int m = 0; m < 3; ++m) {
                f32x4 z = {0.f, 0.f, 0.f, 0.f};
                f32x4 T = mfma16(biA[m][0], whB2[0], z);
                T = mfma16(biA[m][1], whB2[1], T);
                f32x4 G = mfma16(alA[m][0], b0B[tt][0], z);
                G = mfma16(alA[m][1], b0B[tt][1], G);
                acc += T[0] * G[0] + T[1] * G[1] + T[2] * G[2] + T[3] * G[3];
            }
            p[tt] = acc;
        }
#pragma unroll
        for (int tt = 0; tt < 4; ++tt) {
            p[tt] += __shfl_xor(p[tt], 16, 64);
            p[tt] += __shfl_xor(p[tt], 32, 64);
        }
        float v = (quad == 0) ? p[0] : (quad == 1) ? p[1] : (quad == 2) ? p[2] : p[3];
        out[(b * NN + n) * ED + lane] = v;
    }
}

// ==========================================================================
extern "C" void kernel_launch(void* const* d_in, const int* in_sizes, int n_in,
                              void* d_out, int out_size, void* d_ws, size_t ws_size,
                              hipStream_t stream) {
    const float* B0    = (const float*)d_in[0];  // (256,40,64)
    const float* Bi    = (const float*)d_in[1];  // (256,40,64)
    const float* W     = (const float*)d_in[2];  // (40,64,64)
    const float* alpha = (const float*)d_in[3];  // (40,40,40)
    const float* h     = (const float*)d_in[4];  // (40,64,1)
    float* out = (float*)d_out;                  // (256,40,64)

    const size_t need = (size_t)(NN * WHP_N + NN * ALP_N + NB * BFT_N)
                        * sizeof(unsigned short);
    if (ws_size >= need) {
        unsigned short* whp = (unsigned short*)d_ws;
        unsigned short* alp = whp + (size_t)NN * WHP_N;
        unsigned short* bft = alp + (size_t)NN * ALP_N;
        gif_prep5<<<NN + NF + NB, 256, 0, stream>>>(B0, Bi, W, alpha, h,
                                                    whp, alp, bft);
        gif_main9<<<dim3(NB / BPB, 10), 256, 0, stream>>>(whp, alp, bft, out);
        return;
    }

    gif_mfma<<<5 * NB, 256, 0, stream>>>(B0, Bi, W, alpha, h, out);
}